// Round 6
// baseline (268.442 us; speedup 1.0000x reference)
//
#include <hip/hip_runtime.h>
#include <cmath>

static constexpr int EMB  = 768;
static constexpr int HS   = 64;
static constexpr int NB   = 4;
static constexpr int SEQ  = 4096;
static constexpr int MTOT = NB * SEQ;   // 16384 rows

typedef __attribute__((ext_vector_type(8))) short  short8x;
typedef __attribute__((ext_vector_type(4))) float  float4x;
typedef __attribute__((ext_vector_type(4))) unsigned short ushort4x;

// round-to-nearest-even fp32 -> bf16 bits
__device__ inline unsigned short rne16(float f) {
    unsigned u = __builtin_bit_cast(unsigned, f);
    unsigned r = u + 0x7FFFu + ((u >> 16) & 1u);
    return (unsigned short)(r >> 16);
}
__device__ inline float bf2f(unsigned short h) {
    return __builtin_bit_cast(float, ((unsigned)h) << 16);
}

// ---------------------------------------------------------------------------
// Pack Wk/Wq/Wv (fp32 [768][64]) into MFMA B-fragment layout, split hi/lo bf16.
// Layout: [p(2)][kc(24)][nng(12)][lane(64)][j(8)]  (nng = which*4 + nn)
// ---------------------------------------------------------------------------
__global__ __launch_bounds__(256) void convert_w(
    const float* __restrict__ Wk, const float* __restrict__ Wq, const float* __restrict__ Wv,
    unsigned short* __restrict__ wpk)
{
    const int t    = blockIdx.x * 256 + threadIdx.x;  // 0..36863
    const int lane = t & 63;
    const int rest = t >> 6;        // 0..575
    const int nng  = rest % 12;
    const int kcp  = rest / 12;     // 0..47
    const int kc   = kcp % 24;
    const int p    = kcp / 24;      // 0=hi 1=lo
    const int which= nng >> 2;
    const int nn   = nng & 3;
    const float* W = (which == 0) ? Wk : (which == 1) ? Wq : Wv;
    const int col  = nn * 16 + (lane & 15);
    const int kr   = kc * 32 + (lane >> 4) * 8;

    unsigned short o[8];
    #pragma unroll
    for (int j = 0; j < 8; ++j) {
        float w = W[(size_t)(kr + j) * HS + col];
        unsigned short h = rne16(w);
        o[j] = (p == 0) ? h : rne16(w - bf2f(h));
    }
    size_t base = ((size_t)((p * 24 + kc) * 12 + nng) * 64 + lane) * 8;
    *(short8x*)&wpk[base] = *(short8x*)o;
}

// ---------------------------------------------------------------------------
// Projection GEMM: 32-row tiles, double-buffered x staging, 3-pass split-bf16.
// Outputs khi/klo/qhi/qlo bf16 [16384][64]; vT bf16 [4][64][4096].
// ---------------------------------------------------------------------------
__global__ __launch_bounds__(256) void proj_kernel(
    const float* __restrict__ x,
    const unsigned short* __restrict__ wpk,
    const float* __restrict__ bk, const float* __restrict__ bq, const float* __restrict__ bv,
    unsigned short* __restrict__ khi, unsigned short* __restrict__ klo,
    unsigned short* __restrict__ qhi, unsigned short* __restrict__ qlo,
    unsigned short* __restrict__ vT)
{
    __shared__ unsigned short xh[2][32 * 72];
    __shared__ unsigned short xl[2][32 * 72];

    const int tid  = threadIdx.x;
    const int lane = tid & 63;
    const int w    = tid >> 6;       // wave 0..3 -> nn stripe
    const int l15  = lane & 15;
    const int quad = lane >> 4;
    const int row0 = blockIdx.x * 32;

    float4x acc[3][2] = {};          // [which][mi]
    float4  pre[2];

    #pragma unroll
    for (int it = 0; it < 2; ++it) {
        const int fi = tid + it * 256;
        const int r  = fi >> 4, c4 = (fi & 15) * 4;
        pre[it] = *(const float4*)&x[(size_t)(row0 + r) * EMB + 0 * 64 + c4];
    }
    #pragma unroll
    for (int it = 0; it < 2; ++it) {
        const int fi = tid + it * 256;
        const int r  = fi >> 4, c4 = (fi & 15) * 4;
        const float4 xv = pre[it];
        const unsigned short h0 = rne16(xv.x), h1 = rne16(xv.y),
                             h2 = rne16(xv.z), h3 = rne16(xv.w);
        ushort4x hv = {h0, h1, h2, h3};
        ushort4x lv = {rne16(xv.x - bf2f(h0)), rne16(xv.y - bf2f(h1)),
                       rne16(xv.z - bf2f(h2)), rne16(xv.w - bf2f(h3))};
        *(ushort4x*)&xh[0][r * 72 + c4] = hv;
        *(ushort4x*)&xl[0][r * 72 + c4] = lv;
    }

    for (int ch = 0; ch < 12; ++ch) {
        if (ch + 1 < 12) {
            #pragma unroll
            for (int it = 0; it < 2; ++it) {
                const int fi = tid + it * 256;
                const int r  = fi >> 4, c4 = (fi & 15) * 4;
                pre[it] = *(const float4*)&x[(size_t)(row0 + r) * EMB + (ch + 1) * 64 + c4];
            }
        }
        __syncthreads();
        const int buf = ch & 1;

        #pragma unroll
        for (int k0i = 0; k0i < 2; ++k0i) {
            const int k0 = k0i * 32;
            const int kc = ch * 2 + k0i;
            short8x ah[2], al[2];
            #pragma unroll
            for (int mi = 0; mi < 2; ++mi) {
                ah[mi] = *(const short8x*)&xh[buf][(mi * 16 + l15) * 72 + k0 + quad * 8];
                al[mi] = *(const short8x*)&xl[buf][(mi * 16 + l15) * 72 + k0 + quad * 8];
            }
            #pragma unroll
            for (int which = 0; which < 3; ++which) {
                const int nng = which * 4 + w;
                const short8x bh = *(const short8x*)&wpk[((size_t)((0 * 24 + kc) * 12 + nng) * 64 + lane) * 8];
                const short8x bl = *(const short8x*)&wpk[((size_t)((1 * 24 + kc) * 12 + nng) * 64 + lane) * 8];
                #pragma unroll
                for (int mi = 0; mi < 2; ++mi) {
                    acc[which][mi] = __builtin_amdgcn_mfma_f32_16x16x32_bf16(ah[mi], bh, acc[which][mi], 0, 0, 0);
                    acc[which][mi] = __builtin_amdgcn_mfma_f32_16x16x32_bf16(ah[mi], bl, acc[which][mi], 0, 0, 0);
                    acc[which][mi] = __builtin_amdgcn_mfma_f32_16x16x32_bf16(al[mi], bh, acc[which][mi], 0, 0, 0);
                }
            }
        }

        if (ch + 1 < 12) {
            const int nbuf = (ch + 1) & 1;
            #pragma unroll
            for (int it = 0; it < 2; ++it) {
                const int fi = tid + it * 256;
                const int r  = fi >> 4, c4 = (fi & 15) * 4;
                const float4 xv = pre[it];
                const unsigned short h0 = rne16(xv.x), h1 = rne16(xv.y),
                                     h2 = rne16(xv.z), h3 = rne16(xv.w);
                ushort4x hv = {h0, h1, h2, h3};
                ushort4x lv = {rne16(xv.x - bf2f(h0)), rne16(xv.y - bf2f(h1)),
                               rne16(xv.z - bf2f(h2)), rne16(xv.w - bf2f(h3))};
                *(ushort4x*)&xh[nbuf][r * 72 + c4] = hv;
                *(ushort4x*)&xl[nbuf][r * 72 + c4] = lv;
            }
        }
    }

    const int col = w * 16 + l15;
    const float bkv = bk[col], bqv = bq[col], bvv = bv[col];
    #pragma unroll
    for (int mi = 0; mi < 2; ++mi) {
        const int rbase = row0 + mi * 16 + quad * 4;
        #pragma unroll
        for (int r = 0; r < 4; ++r) {
            const float kv = acc[0][mi][r] + bkv;
            const unsigned short hk = rne16(kv);
            khi[(size_t)(rbase + r) * 64 + col] = hk;
            klo[(size_t)(rbase + r) * 64 + col] = rne16(kv - bf2f(hk));
            const float qv = acc[1][mi][r] + bqv;
            const unsigned short hq = rne16(qv);
            qhi[(size_t)(rbase + r) * 64 + col] = hq;
            qlo[(size_t)(rbase + r) * 64 + col] = rne16(qv - bf2f(hq));
        }
        const int b = rbase / SEQ;
        const int s = rbase % SEQ;
        ushort4x vv = {rne16(acc[2][mi][0] + bvv), rne16(acc[2][mi][1] + bvv),
                       rne16(acc[2][mi][2] + bvv), rne16(acc[2][mi][3] + bvv)};
        *(ushort4x*)&vT[((size_t)b * 64 + col) * SEQ + s] = vv;
    }
}

// ---------------------------------------------------------------------------
// Flash attention v6: pair-balanced (jA=p, jB=63-p share staged s-tiles),
// static-max softmax, 3-pass split S (R3-proven numerics), barrier-free
// applications. Partials: fp32 (O, l) per (j, b, split) -> combine sums.
// NO atomics (R5 lesson: device-scope atomicAdd = ~50B of HBM RMW per lane).
// ---------------------------------------------------------------------------
__global__ __launch_bounds__(256, 4) void attn_kernel(
    const unsigned short* __restrict__ khi, const unsigned short* __restrict__ klo,
    const unsigned short* __restrict__ qhi, const unsigned short* __restrict__ qlo,
    const unsigned short* __restrict__ vT,
    float* __restrict__ Opart, float* __restrict__ lpart, int SPLITS)
{
    __shared__ unsigned short qh_s[64 * 72];   // K-role hi tile [s][h]
    __shared__ unsigned short ql_s[64 * 72];   // K-role lo tile [s][h]
    __shared__ unsigned short vt_s[64 * 72];   // V tile [h][s]
    __shared__ unsigned short ps[64 * 72];     // P tile (intra-wave rows)

    const int tid  = threadIdx.x;
    const int lane = tid & 63;
    const int w    = tid >> 6;
    const int l15  = lane & 15;
    const int quad = lane >> 4;

    const int n  = blockIdx.x;
    const int sp = n % SPLITS;
    const int b  = (n / SPLITS) % NB;
    const int p  = n / (SPLITS * NB);  // pair 0..31
    const int jA = p, jB = 63 - p;
    const size_t rowb = (size_t)b * SEQ;

    // Q-role A-frags for both tiles (rows j*64+16w+l15), split hi/lo
    short8x aAh[2], aAl[2], aBh[2], aBl[2];
    {
        const size_t rA = rowb + jA * 64 + 16 * w + l15;
        const size_t rB = rowb + jB * 64 + 16 * w + l15;
        #pragma unroll
        for (int k0 = 0; k0 < 2; ++k0) {
            aAh[k0] = *(const short8x*)&khi[rA * 64 + k0 * 32 + quad * 8];
            aAl[k0] = *(const short8x*)&klo[rA * 64 + k0 * 32 + quad * 8];
            aBh[k0] = *(const short8x*)&khi[rB * 64 + k0 * 32 + quad * 8];
            aBl[k0] = *(const short8x*)&klo[rB * 64 + k0 * 32 + quad * 8];
        }
    }

    float lA[4] = {0.f, 0.f, 0.f, 0.f}, lB[4] = {0.f, 0.f, 0.f, 0.f};
    float4x oA[4] = {}, oB[4] = {};

    const int sr = tid >> 3;         // staging row 0..31
    const int c8 = (tid & 7) * 8;    // staging col (bf16 units)

    auto apply = [&](int j, const short8x* ah, const short8x* al,
                     float4x* oacc, float* l_r, bool diag, int s0) {
        float4x sacc[4] = {};
        #pragma unroll
        for (int k0 = 0; k0 < 2; ++k0) {
            #pragma unroll
            for (int nn = 0; nn < 4; ++nn) {
                const short8x bh = *(const short8x*)&qh_s[(nn * 16 + l15) * 72 + k0 * 32 + quad * 8];
                const short8x bl = *(const short8x*)&ql_s[(nn * 16 + l15) * 72 + k0 * 32 + quad * 8];
                sacc[nn] = __builtin_amdgcn_mfma_f32_16x16x32_bf16(ah[k0], bh, sacc[nn], 0, 0, 0);
                sacc[nn] = __builtin_amdgcn_mfma_f32_16x16x32_bf16(al[k0], bh, sacc[nn], 0, 0, 0);
                sacc[nn] = __builtin_amdgcn_mfma_f32_16x16x32_bf16(ah[k0], bl, sacc[nn], 0, 0, 0);
            }
        }
        if (diag) {
            const int trow = j * 64 + 16 * w + quad * 4;
            #pragma unroll
            for (int nn = 0; nn < 4; ++nn) {
                const int colg = s0 + nn * 16 + l15;
                #pragma unroll
                for (int r = 0; r < 4; ++r)
                    if (colg > trow + r) sacc[nn][r] = -1e30f;
            }
        }
        #pragma unroll
        for (int nn = 0; nn < 4; ++nn) {
            #pragma unroll
            for (int r = 0; r < 4; ++r) {
                const float e = __expf(fminf(sacc[nn][r], 80.0f));
                const unsigned short h = rne16(e);
                l_r[r] += bf2f(h);
                ps[(16 * w + quad * 4 + r) * 72 + nn * 16 + l15] = h;
            }
        }
        // ps rows are written & read by the SAME wave -> no barrier needed
        #pragma unroll
        for (int k0 = 0; k0 < 2; ++k0) {
            const short8x pa = *(const short8x*)&ps[(16 * w + l15) * 72 + k0 * 32 + quad * 8];
            #pragma unroll
            for (int nn = 0; nn < 4; ++nn) {
                const short8x vb = *(const short8x*)&vt_s[(nn * 16 + l15) * 72 + k0 * 32 + quad * 8];
                oacc[nn] = __builtin_amdgcn_mfma_f32_16x16x32_bf16(pa, vb, oacc[nn], 0, 0, 0);
            }
        }
    };

    for (int ci = sp; ci <= jB; ci += SPLITS) {
        const int s0 = ci * 64;
        __syncthreads();
        #pragma unroll
        for (int it = 0; it < 2; ++it) {
            const int r = sr + it * 32;
            *(short8x*)&qh_s[r * 72 + c8] = *(const short8x*)&qhi[(rowb + s0 + r) * 64 + c8];
            *(short8x*)&ql_s[r * 72 + c8] = *(const short8x*)&qlo[(rowb + s0 + r) * 64 + c8];
            *(short8x*)&vt_s[r * 72 + c8] = *(const short8x*)&vT[((size_t)b * 64 + r) * SEQ + s0 + c8];
        }
        __syncthreads();

        apply(jB, aBh, aBl, oB, lB, ci == jB, s0);
        if (ci <= jA) apply(jA, aAh, aAl, oA, lA, ci == jA, s0);
    }

    // epilogue: per tile, reduce l across 16 cols, write fp32 partials
    #pragma unroll
    for (int tile = 0; tile < 2; ++tile) {
        float*   l_r  = tile ? lA : lB;
        float4x* oacc = tile ? oA : oB;
        const int j   = tile ? jA : jB;
        if (tile && sp > jA) break;          // this block never touched jA
        #pragma unroll
        for (int r = 0; r < 4; ++r) {
            float l = l_r[r];
            l += __shfl_xor(l, 1);
            l += __shfl_xor(l, 2);
            l += __shfl_xor(l, 4);
            l += __shfl_xor(l, 8);
            l_r[r] = l;
        }
        const size_t part = (size_t)(j * NB + b) * SPLITS + sp;
        float* Op = Opart + part * 4096;
        #pragma unroll
        for (int nn = 0; nn < 4; ++nn)
            #pragma unroll
            for (int r = 0; r < 4; ++r)
                Op[(16 * w + quad * 4 + r) * 64 + nn * 16 + l15] = oacc[nn][r];
        if (l15 == 0) {
            #pragma unroll
            for (int r = 0; r < 4; ++r)
                lpart[part * 64 + 16 * w + quad * 4 + r] = l_r[r];
        }
    }
}

// ---------------------------------------------------------------------------
// Combine: out = (sum_sp O_p) / (sum_sp l_p); skips never-written slots (l==0)
// ---------------------------------------------------------------------------
__global__ __launch_bounds__(256) void combine_kernel(
    const float* __restrict__ Opart, const float* __restrict__ lpart,
    float* __restrict__ out, int SPLITS)
{
    const int j   = blockIdx.x;
    const int b   = blockIdx.y;
    const int tid = threadIdx.x;
    const int row = tid >> 2;            // 0..63
    const int c0  = (tid & 3) * 16;
    const size_t base = (size_t)(j * NB + b) * SPLITS;

    float4 acc[4] = {};
    float lsum = 0.f;
    for (int sp = 0; sp < SPLITS; ++sp) {
        const float l = lpart[(base + sp) * 64 + row];
        if (l > 0.f) {
            lsum += l;
            const float* Op = Opart + (base + sp) * 4096 + row * 64 + c0;
            #pragma unroll
            for (int u = 0; u < 4; ++u) {
                const float4 v = *(const float4*)&Op[u * 4];
                acc[u].x += v.x; acc[u].y += v.y; acc[u].z += v.z; acc[u].w += v.w;
            }
        }
    }
    const float inv = 1.0f / lsum;
    float* o = out + ((size_t)b * SEQ + j * 64 + row) * 64 + c0;
    #pragma unroll
    for (int u = 0; u < 4; ++u) {
        float4 v;
        v.x = acc[u].x * inv; v.y = acc[u].y * inv;
        v.z = acc[u].z * inv; v.w = acc[u].w * inv;
        *(float4*)&o[u * 4] = v;
    }
}

// ---------------------------------------------------------------------------
extern "C" void kernel_launch(void* const* d_in, const int* in_sizes, int n_in,
                              void* d_out, int out_size, void* d_ws, size_t ws_size,
                              hipStream_t stream)
{
    const float* x  = (const float*)d_in[0];
    const float* Wk = (const float*)d_in[1];
    const float* bk = (const float*)d_in[2];
    const float* Wq = (const float*)d_in[3];
    const float* bq = (const float*)d_in[4];
    const float* Wv = (const float*)d_in[5];
    const float* bv = (const float*)d_in[6];
    float* out = (float*)d_out;

    const size_t NE = (size_t)MTOT * HS;      // 1M elements
    unsigned short* khi = (unsigned short*)d_ws;
    unsigned short* klo = khi + NE;
    unsigned short* qhi = klo + NE;
    unsigned short* qlo = qhi + NE;
    unsigned short* vT  = qlo + NE;
    unsigned short* wpk = vT + NE;            // 294912 shorts
    const size_t fixed_bytes = 5 * NE * sizeof(unsigned short) + 294912 * sizeof(unsigned short);

    // largest SPLITS (8 then 4) whose fp32 partials fit the workspace
    int SPLITS = 8;
    while (SPLITS > 4) {
        const size_t need = fixed_bytes +
            (size_t)NB * 64 * SPLITS * (64 * 64 + 64) * sizeof(float);
        if (need <= ws_size) break;
        SPLITS >>= 1;
    }
    float* Opart = (float*)((char*)d_ws + fixed_bytes);
    float* lpart = Opart + (size_t)NB * 64 * SPLITS * 64 * 64;

    hipMemsetAsync(lpart, 0, (size_t)NB * 64 * SPLITS * 64 * sizeof(float), stream);
    convert_w<<<144, 256, 0, stream>>>(Wk, Wq, Wv, wpk);
    proj_kernel<<<MTOT / 32, 256, 0, stream>>>(x, wpk, bk, bq, bv, khi, klo, qhi, qlo, vT);
    attn_kernel<<<32 * NB * SPLITS, 256, 0, stream>>>(khi, klo, qhi, qlo, vT, Opart, lpart, SPLITS);
    dim3 cgrid(64, NB);
    combine_kernel<<<cgrid, 256, 0, stream>>>(Opart, lpart, out, SPLITS);
}

// Round 7
// 160.556 us; speedup vs baseline: 1.6720x; 1.6720x over previous
//
#include <hip/hip_runtime.h>
#include <cmath>

static constexpr int EMB  = 768;
static constexpr int HS   = 64;
static constexpr int NB   = 4;
static constexpr int SEQ  = 4096;
static constexpr int MTOT = NB * SEQ;   // 16384 rows
static constexpr int SPLITS = 8;        // ws >= 45.6 MB proven by R6 (occupancy 39% > S=4's 25% cap)

typedef __attribute__((ext_vector_type(8))) short  short8x;
typedef __attribute__((ext_vector_type(4))) float  float4x;
typedef __attribute__((ext_vector_type(4))) unsigned short ushort4x;

// round-to-nearest-even fp32 -> bf16 bits
__device__ inline unsigned short rne16(float f) {
    unsigned u = __builtin_bit_cast(unsigned, f);
    unsigned r = u + 0x7FFFu + ((u >> 16) & 1u);
    return (unsigned short)(r >> 16);
}
__device__ inline float bf2f(unsigned short h) {
    return __builtin_bit_cast(float, ((unsigned)h) << 16);
}

// ---------------------------------------------------------------------------
// Pack Wk/Wq/Wv (fp32 [768][64]) into MFMA B-fragment layout, split hi/lo bf16.
// Layout: [p(2)][kc(24)][nng(12)][lane(64)][j(8)]  (nng = which*4 + nn)
// ---------------------------------------------------------------------------
__global__ __launch_bounds__(256) void convert_w(
    const float* __restrict__ Wk, const float* __restrict__ Wq, const float* __restrict__ Wv,
    unsigned short* __restrict__ wpk)
{
    const int t    = blockIdx.x * 256 + threadIdx.x;  // 0..36863
    const int lane = t & 63;
    const int rest = t >> 6;        // 0..575
    const int nng  = rest % 12;
    const int kcp  = rest / 12;     // 0..47
    const int kc   = kcp % 24;
    const int p    = kcp / 24;      // 0=hi 1=lo
    const int which= nng >> 2;
    const int nn   = nng & 3;
    const float* W = (which == 0) ? Wk : (which == 1) ? Wq : Wv;
    const int col  = nn * 16 + (lane & 15);
    const int kr   = kc * 32 + (lane >> 4) * 8;

    unsigned short o[8];
    #pragma unroll
    for (int j = 0; j < 8; ++j) {
        float w = W[(size_t)(kr + j) * HS + col];
        unsigned short h = rne16(w);
        o[j] = (p == 0) ? h : rne16(w - bf2f(h));
    }
    size_t base = ((size_t)((p * 24 + kc) * 12 + nng) * 64 + lane) * 8;
    *(short8x*)&wpk[base] = *(short8x*)o;
}

// ---------------------------------------------------------------------------
// Projection GEMM: 32-row tiles, double-buffered x staging, 3-pass split-bf16.
// Outputs khi/klo/qhi/qlo bf16 [16384][64]; vT bf16 [4][64][4096].
// ---------------------------------------------------------------------------
__global__ __launch_bounds__(256) void proj_kernel(
    const float* __restrict__ x,
    const unsigned short* __restrict__ wpk,
    const float* __restrict__ bk, const float* __restrict__ bq, const float* __restrict__ bv,
    unsigned short* __restrict__ khi, unsigned short* __restrict__ klo,
    unsigned short* __restrict__ qhi, unsigned short* __restrict__ qlo,
    unsigned short* __restrict__ vT)
{
    __shared__ unsigned short xh[2][32 * 72];
    __shared__ unsigned short xl[2][32 * 72];

    const int tid  = threadIdx.x;
    const int lane = tid & 63;
    const int w    = tid >> 6;       // wave 0..3 -> nn stripe
    const int l15  = lane & 15;
    const int quad = lane >> 4;
    const int row0 = blockIdx.x * 32;

    float4x acc[3][2] = {};          // [which][mi]
    float4  pre[2];

    #pragma unroll
    for (int it = 0; it < 2; ++it) {
        const int fi = tid + it * 256;
        const int r  = fi >> 4, c4 = (fi & 15) * 4;
        pre[it] = *(const float4*)&x[(size_t)(row0 + r) * EMB + 0 * 64 + c4];
    }
    #pragma unroll
    for (int it = 0; it < 2; ++it) {
        const int fi = tid + it * 256;
        const int r  = fi >> 4, c4 = (fi & 15) * 4;
        const float4 xv = pre[it];
        const unsigned short h0 = rne16(xv.x), h1 = rne16(xv.y),
                             h2 = rne16(xv.z), h3 = rne16(xv.w);
        ushort4x hv = {h0, h1, h2, h3};
        ushort4x lv = {rne16(xv.x - bf2f(h0)), rne16(xv.y - bf2f(h1)),
                       rne16(xv.z - bf2f(h2)), rne16(xv.w - bf2f(h3))};
        *(ushort4x*)&xh[0][r * 72 + c4] = hv;
        *(ushort4x*)&xl[0][r * 72 + c4] = lv;
    }

    for (int ch = 0; ch < 12; ++ch) {
        if (ch + 1 < 12) {
            #pragma unroll
            for (int it = 0; it < 2; ++it) {
                const int fi = tid + it * 256;
                const int r  = fi >> 4, c4 = (fi & 15) * 4;
                pre[it] = *(const float4*)&x[(size_t)(row0 + r) * EMB + (ch + 1) * 64 + c4];
            }
        }
        __syncthreads();
        const int buf = ch & 1;

        #pragma unroll
        for (int k0i = 0; k0i < 2; ++k0i) {
            const int k0 = k0i * 32;
            const int kc = ch * 2 + k0i;
            short8x ah[2], al[2];
            #pragma unroll
            for (int mi = 0; mi < 2; ++mi) {
                ah[mi] = *(const short8x*)&xh[buf][(mi * 16 + l15) * 72 + k0 + quad * 8];
                al[mi] = *(const short8x*)&xl[buf][(mi * 16 + l15) * 72 + k0 + quad * 8];
            }
            #pragma unroll
            for (int which = 0; which < 3; ++which) {
                const int nng = which * 4 + w;
                const short8x bh = *(const short8x*)&wpk[((size_t)((0 * 24 + kc) * 12 + nng) * 64 + lane) * 8];
                const short8x bl = *(const short8x*)&wpk[((size_t)((1 * 24 + kc) * 12 + nng) * 64 + lane) * 8];
                #pragma unroll
                for (int mi = 0; mi < 2; ++mi) {
                    acc[which][mi] = __builtin_amdgcn_mfma_f32_16x16x32_bf16(ah[mi], bh, acc[which][mi], 0, 0, 0);
                    acc[which][mi] = __builtin_amdgcn_mfma_f32_16x16x32_bf16(ah[mi], bl, acc[which][mi], 0, 0, 0);
                    acc[which][mi] = __builtin_amdgcn_mfma_f32_16x16x32_bf16(al[mi], bh, acc[which][mi], 0, 0, 0);
                }
            }
        }

        if (ch + 1 < 12) {
            const int nbuf = (ch + 1) & 1;
            #pragma unroll
            for (int it = 0; it < 2; ++it) {
                const int fi = tid + it * 256;
                const int r  = fi >> 4, c4 = (fi & 15) * 4;
                const float4 xv = pre[it];
                const unsigned short h0 = rne16(xv.x), h1 = rne16(xv.y),
                                     h2 = rne16(xv.z), h3 = rne16(xv.w);
                ushort4x hv = {h0, h1, h2, h3};
                ushort4x lv = {rne16(xv.x - bf2f(h0)), rne16(xv.y - bf2f(h1)),
                               rne16(xv.z - bf2f(h2)), rne16(xv.w - bf2f(h3))};
                *(ushort4x*)&xh[nbuf][r * 72 + c4] = hv;
                *(ushort4x*)&xl[nbuf][r * 72 + c4] = lv;
            }
        }
    }

    const int col = w * 16 + l15;
    const float bkv = bk[col], bqv = bq[col], bvv = bv[col];
    #pragma unroll
    for (int mi = 0; mi < 2; ++mi) {
        const int rbase = row0 + mi * 16 + quad * 4;
        #pragma unroll
        for (int r = 0; r < 4; ++r) {
            const float kv = acc[0][mi][r] + bkv;
            const unsigned short hk = rne16(kv);
            khi[(size_t)(rbase + r) * 64 + col] = hk;
            klo[(size_t)(rbase + r) * 64 + col] = rne16(kv - bf2f(hk));
            const float qv = acc[1][mi][r] + bqv;
            const unsigned short hq = rne16(qv);
            qhi[(size_t)(rbase + r) * 64 + col] = hq;
            qlo[(size_t)(rbase + r) * 64 + col] = rne16(qv - bf2f(hq));
        }
        const int b = rbase / SEQ;
        const int s = rbase % SEQ;
        ushort4x vv = {rne16(acc[2][mi][0] + bvv), rne16(acc[2][mi][1] + bvv),
                       rne16(acc[2][mi][2] + bvv), rne16(acc[2][mi][3] + bvv)};
        *(ushort4x*)&vT[((size_t)b * 64 + col) * SEQ + s] = vv;
    }
}

// ---------------------------------------------------------------------------
// Flash attention v7: j-quad {p, 31-p, 32+p, 63-p} per block (uniform total
// work AND near-uniform applies-per-staging -> blocks stay phase-locked ->
// L2 serves cross-block tile re-reads; each staged tile feeds up to 4 applies).
// Static-max softmax, 3-pass split S (R3-proven), fp32 partials, no atomics.
// ---------------------------------------------------------------------------
__global__ __launch_bounds__(256, 2) void attn_kernel(
    const unsigned short* __restrict__ khi, const unsigned short* __restrict__ klo,
    const unsigned short* __restrict__ qhi, const unsigned short* __restrict__ qlo,
    const unsigned short* __restrict__ vT,
    float* __restrict__ Opart, float* __restrict__ lpart)
{
    __shared__ unsigned short qh_s[64 * 72];   // K-role hi tile [s][h]
    __shared__ unsigned short ql_s[64 * 72];   // K-role lo tile [s][h]
    __shared__ unsigned short vt_s[64 * 72];   // V tile [h][s]
    __shared__ unsigned short psH[64 * 72];    // P tiles (intra-wave rows)
    __shared__ unsigned short psL[64 * 72];

    const int tid  = threadIdx.x;
    const int lane = tid & 63;
    const int w    = tid >> 6;
    const int l15  = lane & 15;
    const int quad = lane >> 4;

    const int n  = blockIdx.x;                 // 0..511
    const int sp = n & (SPLITS - 1);
    const int b  = (n >> 3) & (NB - 1);
    const int p  = n >> 5;                     // 0..15
    const int jj[4] = {63 - p, 32 + p, 31 - p, p};   // descending j
    const size_t rowb = (size_t)b * SEQ;

    float4x oacc[4][4] = {};                   // [idx][nn]
    float   l_r[4][4]  = {};                   // [idx][r]

    const int sr = tid >> 3;         // staging row 0..31
    const int c8 = (tid & 7) * 8;    // staging col (bf16 units)

    for (int ci = sp; ci <= jj[0]; ci += SPLITS) {
        const int s0 = ci * 64;
        __syncthreads();
        #pragma unroll
        for (int it = 0; it < 2; ++it) {
            const int r = sr + it * 32;
            *(short8x*)&qh_s[r * 72 + c8] = *(const short8x*)&qhi[(rowb + s0 + r) * 64 + c8];
            *(short8x*)&ql_s[r * 72 + c8] = *(const short8x*)&qlo[(rowb + s0 + r) * 64 + c8];
            *(short8x*)&vt_s[r * 72 + c8] = *(const short8x*)&vT[((size_t)b * 64 + r) * SEQ + s0 + c8];
        }
        __syncthreads();

        #pragma unroll
        for (int g = 0; g < 2; ++g) {
            const int idxH = g ? 1 : 0;        // jj[1]=32+p : jj[0]=63-p
            const int idxL = g ? 2 : 3;        // jj[2]=31-p : jj[3]=p
            const int jH = jj[idxH], jL = jj[idxL];
            const bool aH = (ci <= jH), aL = (ci <= jL);
            if (!aH && !aL) continue;          // wave-uniform

            // A-frags from global (L2-hot: khi/klo are 2 MB each)
            short8x ahH[2], alH[2], ahL[2], alL[2];
            #pragma unroll
            for (int k0 = 0; k0 < 2; ++k0) {
                if (aH) {
                    const size_t rH = (rowb + jH * 64 + 16 * w + l15) * 64 + k0 * 32 + quad * 8;
                    ahH[k0] = *(const short8x*)&khi[rH];
                    alH[k0] = *(const short8x*)&klo[rH];
                }
                if (aL) {
                    const size_t rL = (rowb + jL * 64 + 16 * w + l15) * 64 + k0 * 32 + quad * 8;
                    ahL[k0] = *(const short8x*)&khi[rL];
                    alL[k0] = *(const short8x*)&klo[rL];
                }
            }

            // S = Qrole . KroleT, 3-pass split; B-frags read once for both j's
            float4x sH[4] = {}, sL[4] = {};
            #pragma unroll
            for (int k0 = 0; k0 < 2; ++k0) {
                #pragma unroll
                for (int nn = 0; nn < 4; ++nn) {
                    const short8x bh = *(const short8x*)&qh_s[(nn * 16 + l15) * 72 + k0 * 32 + quad * 8];
                    const short8x bl = *(const short8x*)&ql_s[(nn * 16 + l15) * 72 + k0 * 32 + quad * 8];
                    if (aH) {
                        sH[nn] = __builtin_amdgcn_mfma_f32_16x16x32_bf16(ahH[k0], bh, sH[nn], 0, 0, 0);
                        sH[nn] = __builtin_amdgcn_mfma_f32_16x16x32_bf16(alH[k0], bh, sH[nn], 0, 0, 0);
                        sH[nn] = __builtin_amdgcn_mfma_f32_16x16x32_bf16(ahH[k0], bl, sH[nn], 0, 0, 0);
                    }
                    if (aL) {
                        sL[nn] = __builtin_amdgcn_mfma_f32_16x16x32_bf16(ahL[k0], bh, sL[nn], 0, 0, 0);
                        sL[nn] = __builtin_amdgcn_mfma_f32_16x16x32_bf16(alL[k0], bh, sL[nn], 0, 0, 0);
                        sL[nn] = __builtin_amdgcn_mfma_f32_16x16x32_bf16(ahL[k0], bl, sL[nn], 0, 0, 0);
                    }
                }
            }

            // mask diag tile, exp, write P tiles, accumulate l
            #pragma unroll
            for (int hl = 0; hl < 2; ++hl) {
                const bool alive = hl ? aL : aH;
                if (!alive) continue;
                const int j   = hl ? jL : jH;
                const int idx = hl ? idxL : idxH;
                float4x* sc   = hl ? sL : sH;
                unsigned short* ps = hl ? psL : psH;
                if (ci == j) {
                    const int trow = j * 64 + 16 * w + quad * 4;
                    #pragma unroll
                    for (int nn = 0; nn < 4; ++nn) {
                        const int colg = s0 + nn * 16 + l15;
                        #pragma unroll
                        for (int r = 0; r < 4; ++r)
                            if (colg > trow + r) sc[nn][r] = -1e30f;
                    }
                }
                #pragma unroll
                for (int nn = 0; nn < 4; ++nn) {
                    #pragma unroll
                    for (int r = 0; r < 4; ++r) {
                        const float e = __expf(fminf(sc[nn][r], 80.0f));
                        const unsigned short h = rne16(e);
                        l_r[idx][r] += bf2f(h);
                        ps[(16 * w + quad * 4 + r) * 72 + nn * 16 + l15] = h;
                    }
                }
            }

            // PV: V-frags read once for both j's (ps same-wave -> no barrier)
            #pragma unroll
            for (int k0 = 0; k0 < 2; ++k0) {
                short8x paH, paL;
                if (aH) paH = *(const short8x*)&psH[(16 * w + l15) * 72 + k0 * 32 + quad * 8];
                if (aL) paL = *(const short8x*)&psL[(16 * w + l15) * 72 + k0 * 32 + quad * 8];
                #pragma unroll
                for (int nn = 0; nn < 4; ++nn) {
                    const short8x vb = *(const short8x*)&vt_s[(nn * 16 + l15) * 72 + k0 * 32 + quad * 8];
                    if (aH) oacc[idxH][nn] = __builtin_amdgcn_mfma_f32_16x16x32_bf16(paH, vb, oacc[idxH][nn], 0, 0, 0);
                    if (aL) oacc[idxL][nn] = __builtin_amdgcn_mfma_f32_16x16x32_bf16(paL, vb, oacc[idxL][nn], 0, 0, 0);
                }
            }
        }
    }

    // epilogue: per j-tile, reduce l across 16 cols, write fp32 partials
    #pragma unroll
    for (int idx = 0; idx < 4; ++idx) {
        const int j = jj[idx];
        if (idx == 3 && sp > p) continue;      // j0=p never touched by this sp
        float lv[4];
        #pragma unroll
        for (int r = 0; r < 4; ++r) {
            float l = l_r[idx][r];
            l += __shfl_xor(l, 1);
            l += __shfl_xor(l, 2);
            l += __shfl_xor(l, 4);
            l += __shfl_xor(l, 8);
            lv[r] = l;
        }
        const size_t part = (size_t)(j * NB + b) * SPLITS + sp;
        float* Op = Opart + part * 4096;
        #pragma unroll
        for (int nn = 0; nn < 4; ++nn)
            #pragma unroll
            for (int r = 0; r < 4; ++r)
                Op[(16 * w + quad * 4 + r) * 64 + nn * 16 + l15] = oacc[idx][nn][r];
        if (l15 == 0) {
            #pragma unroll
            for (int r = 0; r < 4; ++r)
                lpart[part * 64 + 16 * w + quad * 4 + r] = lv[r];
        }
    }
}

// ---------------------------------------------------------------------------
// Combine: out = (sum_sp O_p) / (sum_sp l_p); skips never-written slots (l==0)
// ---------------------------------------------------------------------------
__global__ __launch_bounds__(256) void combine_kernel(
    const float* __restrict__ Opart, const float* __restrict__ lpart,
    float* __restrict__ out)
{
    const int j   = blockIdx.x;
    const int b   = blockIdx.y;
    const int tid = threadIdx.x;
    const int row = tid >> 2;            // 0..63
    const int c0  = (tid & 3) * 16;
    const size_t base = (size_t)(j * NB + b) * SPLITS;

    float4 acc[4] = {};
    float lsum = 0.f;
    for (int sp = 0; sp < SPLITS; ++sp) {
        const float l = lpart[(base + sp) * 64 + row];
        if (l > 0.f) {
            lsum += l;
            const float* Op = Opart + (base + sp) * 4096 + row * 64 + c0;
            #pragma unroll
            for (int u = 0; u < 4; ++u) {
                const float4 v = *(const float4*)&Op[u * 4];
                acc[u].x += v.x; acc[u].y += v.y; acc[u].z += v.z; acc[u].w += v.w;
            }
        }
    }
    const float inv = 1.0f / lsum;
    float* o = out + ((size_t)b * SEQ + j * 64 + row) * 64 + c0;
    #pragma unroll
    for (int u = 0; u < 4; ++u) {
        float4 v;
        v.x = acc[u].x * inv; v.y = acc[u].y * inv;
        v.z = acc[u].z * inv; v.w = acc[u].w * inv;
        *(float4*)&o[u * 4] = v;
    }
}

// ---------------------------------------------------------------------------
extern "C" void kernel_launch(void* const* d_in, const int* in_sizes, int n_in,
                              void* d_out, int out_size, void* d_ws, size_t ws_size,
                              hipStream_t stream)
{
    const float* x  = (const float*)d_in[0];
    const float* Wk = (const float*)d_in[1];
    const float* bk = (const float*)d_in[2];
    const float* Wq = (const float*)d_in[3];
    const float* bq = (const float*)d_in[4];
    const float* Wv = (const float*)d_in[5];
    const float* bv = (const float*)d_in[6];
    float* out = (float*)d_out;

    const size_t NE = (size_t)MTOT * HS;      // 1M elements
    unsigned short* khi = (unsigned short*)d_ws;
    unsigned short* klo = khi + NE;
    unsigned short* qhi = klo + NE;
    unsigned short* qlo = qhi + NE;
    unsigned short* vT  = qlo + NE;
    unsigned short* wpk = vT + NE;            // 294912 shorts
    float* Opart = (float*)(wpk + 294912);    // 64*NB*SPLITS tiles * 4096 floats
    float* lpart = Opart + (size_t)64 * NB * SPLITS * 4096;
    // total ~45.6 MB (proven available: R6 ran SPLITS=8 per occupancy evidence)

    hipMemsetAsync(lpart, 0, (size_t)64 * NB * SPLITS * 64 * sizeof(float), stream);
    convert_w<<<144, 256, 0, stream>>>(Wk, Wq, Wv, wpk);
    proj_kernel<<<MTOT / 32, 256, 0, stream>>>(x, wpk, bk, bq, bv, khi, klo, qhi, qlo, vT);
    attn_kernel<<<16 * NB * SPLITS, 256, 0, stream>>>(khi, klo, qhi, qlo, vT, Opart, lpart);
    dim3 cgrid(64, NB);
    combine_kernel<<<cgrid, 256, 0, stream>>>(Opart, lpart, out);
}